// Round 6
// baseline (437.986 us; speedup 1.0000x reference)
//
#include <hip/hip_runtime.h>
#include <hip/hip_bf16.h>

// Problem constants
#define B_   4
#define S_   2048
#define H_   16
#define HD_  64
#define D_   1024
#define M_   (B_ * S_)   // 8192 rows
#define N3_  3072

typedef unsigned short u16;
typedef __bf16 bf16x8 __attribute__((ext_vector_type(8)));
typedef float  f32x4  __attribute__((ext_vector_type(4)));
typedef int    i32x4  __attribute__((ext_vector_type(4)));
typedef unsigned short u16x8 __attribute__((ext_vector_type(8)));
typedef unsigned short u16x4 __attribute__((ext_vector_type(4)));

__device__ __forceinline__ float b2f(u16 u) {
    unsigned int x = ((unsigned int)u) << 16;
    return __builtin_bit_cast(float, x);
}
__device__ __forceinline__ u16 f2b(float f) {          // RNE
    unsigned int x = __builtin_bit_cast(unsigned int, f);
    x += 0x7fffu + ((x >> 16) & 1u);
    return (u16)(x >> 16);
}

// async global->LDS, 16B/lane; LDS dest = wave-uniform base + lane*16
typedef const __attribute__((address_space(1))) unsigned int* gas_u32p;
typedef __attribute__((address_space(3))) unsigned int* las_u32p;
__device__ __forceinline__ void gl_lds16(const u16* g, u16* lds_base) {
    __builtin_amdgcn_global_load_lds((gas_u32p)g, (las_u32p)lds_base, 16, 0, 0);
}

// ---------------------------------------------------------------------------
// x fp32 -> bf16, flat
// ---------------------------------------------------------------------------
__global__ __launch_bounds__(256) void cvt_k(const float* __restrict__ in,
                                             u16* __restrict__ out) {
    size_t i = ((size_t)blockIdx.x * 256 + threadIdx.x) * 8;
    float4 a = *(const float4*)(in + i);
    float4 b = *(const float4*)(in + i + 4);
    *(u16x8*)(out + i) = u16x8{f2b(a.x), f2b(a.y), f2b(a.z), f2b(a.w),
                               f2b(b.x), f2b(b.y), f2b(b.z), f2b(b.w)};
}

// ---------------------------------------------------------------------------
// 4 weight transposes fused: z in {0,1,2}: Wq/Wk/Wv -> WqkvT sections
// (z=0 scaled by cscale); z=3: Wo -> WoT.
// ---------------------------------------------------------------------------
__global__ __launch_bounds__(256) void transpose4_k(
    const float* __restrict__ w0, const float* __restrict__ w1,
    const float* __restrict__ w2, const float* __restrict__ w3,
    u16* __restrict__ oqkv, u16* __restrict__ owo, float scale0) {
    __shared__ u16 t[32][33];
    const int z = blockIdx.z;
    const float* in = (z == 0) ? w0 : (z == 1) ? w1 : (z == 2) ? w2 : w3;
    u16* out = (z < 3) ? oqkv + (size_t)z * D_ * D_ : owo;
    const float sc = (z == 0) ? scale0 : 1.0f;
    const int x0 = blockIdx.x * 32, y0 = blockIdx.y * 32;
    const int tx = threadIdx.x & 31, ty = threadIdx.x >> 5;  // 32 x 8
#pragma unroll
    for (int i = 0; i < 32; i += 8)
        t[ty + i][tx] = f2b(in[(size_t)(y0 + ty + i) * D_ + x0 + tx] * sc);
    __syncthreads();
#pragma unroll
    for (int i = 0; i < 32; i += 8)
        out[(size_t)(x0 + ty + i) * D_ + y0 + tx] = t[tx][ty + i];
}

// ---------------------------------------------------------------------------
// QKV GEMM: 256x192 tile, BK=64, 8 waves (2Mx4N), 4-phase schedule with
// counted vmcnt + setprio. XOR-8 chunk swizzle. Grid 32x16 = 512 blocks.
// (Held from r3: three QKV structures converged at ~620-630 TF, limited by
// barrier-aligned LDS-read burst / MFMA burst serialization.)
// ---------------------------------------------------------------------------
#define QBM 256
#define QBN 192
#define QBK 64

__global__ __launch_bounds__(512, 2) void gemm_qkv256(
    const u16* __restrict__ A, const u16* __restrict__ Bt,
    const float* __restrict__ b0, const float* __restrict__ b1,
    const float* __restrict__ b2, float cscale,
    u16* __restrict__ Qo, u16* __restrict__ Ko, u16* __restrict__ Vto,
    int M, int N, int K)
{
    __shared__ __align__(16) u16 As[2][QBM * QBK];   // 64 KB
    __shared__ __align__(16) u16 Bs[2][QBN * QBK];   // 48 KB

    const int tid  = threadIdx.x;
    const int lane = tid & 63;
    const int wave = tid >> 6;                 // 0..7
    const int wr = wave >> 2, wc = wave & 3;   // 2M x 4N
    const int l15 = lane & 15, quad = lane >> 4, s7 = l15 & 7;
    const int r8  = lane >> 3;
    const int csw = ((lane & 7) ^ r8) * 8;     // swizzled global chunk
    const int m0 = blockIdx.x * QBM, n0 = blockIdx.y * QBN;
    (void)M; (void)N;

    const u16* Ag = A  + (size_t)(m0 + wave * 8 + r8) * K + csw;
    const u16* Bg = Bt + (size_t)(n0 + wave * 8 + r8) * K + csw;
    u16* AsW = &As[0][0] + wave * 8 * QBK;
    u16* BsW = &Bs[0][0] + wave * 8 * QBK;
    const size_t rowK64 = (size_t)64 * K;      // 64-row stride (precomputed)

    // stage one 8KB unit (64 rows x 64 cols) = 1 gl_lds per thread
    auto stgA = [&](int buf, int u, int kt) {
        gl_lds16(Ag + (size_t)u * rowK64 + kt * QBK,
                 AsW + buf * (QBM * QBK) + u * 64 * QBK);
    };
    auto stgB = [&](int buf, int u, int kt) {
        gl_lds16(Bg + (size_t)u * rowK64 + kt * QBK,
                 BsW + buf * (QBN * QBK) + u * 64 * QBK);
    };

    f32x4 acc[8][3] = {};

    // prologue: tile0 A+B -> buf0, tile1 B -> buf1 (10 units)
    stgA(0, 0, 0); stgA(0, 1, 0); stgA(0, 2, 0); stgA(0, 3, 0);
    stgB(0, 0, 0); stgB(0, 1, 0); stgB(0, 2, 0);
    stgB(1, 0, 1); stgB(1, 1, 1); stgB(1, 2, 1);
    asm volatile("s_waitcnt vmcnt(3)" ::: "memory");   // buf0 landed
    __builtin_amdgcn_s_barrier();

    const int NIT = K / (2 * QBK);   // 8 iterations, 2 K-tiles each
    for (int it = 0; it < NIT; ++it) {
        const bool last = (it == NIT - 1);
        const int t1 = 2 * it + 1, t2 = 2 * it + 2, t3 = 2 * it + 3;
        bf16x8 bn[3][2];
#pragma unroll
        for (int ph = 0; ph < 4; ++ph) {
            const int hb = ph >> 1;            // buffer select
            const int qg = ph & 1;             // q-group (acc rows 4qg..4qg+3)
            const u16* as = &As[hb][0];
            const u16* bs = &Bs[hb][0];
            if (qg == 0) {
#pragma unroll
                for (int n = 0; n < 3; ++n) {
                    const u16* bp = bs + (wc * 48 + n * 16 + l15) * QBK;
                    bn[n][0] = *(const bf16x8*)(bp + ((quad    ) ^ s7) * 8);
                    bn[n][1] = *(const bf16x8*)(bp + ((quad + 4) ^ s7) * 8);
                }
            }
            bf16x8 af[4][2];
#pragma unroll
            for (int r = 0; r < 4; ++r) {
                const u16* ap = as + (wr * 128 + (qg * 4 + r) * 16 + l15) * QBK;
                af[r][0] = *(const bf16x8*)(ap + ((quad    ) ^ s7) * 8);
                af[r][1] = *(const bf16x8*)(ap + ((quad + 4) ^ s7) * 8);
            }
            if (ph == 0) { stgA(1, 0, t1); stgA(1, 1, t1);
                           stgA(1, 2, t1); stgA(1, 3, t1); }
            if (!last) {
                if (ph == 1) { stgB(0, 0, t2); stgB(0, 1, t2); stgB(0, 2, t2); }
                if (ph == 2) { stgA(0, 0, t2); stgA(0, 1, t2);
                               stgA(0, 2, t2); stgA(0, 3, t2); }
                if (ph == 3) { stgB(1, 0, t3); stgB(1, 1, t3); stgB(1, 2, t3); }
            }
            __builtin_amdgcn_s_barrier();
            asm volatile("s_waitcnt lgkmcnt(0)" ::: "memory");
            __builtin_amdgcn_sched_barrier(0);
            __builtin_amdgcn_s_setprio(1);
#pragma unroll
            for (int r = 0; r < 4; ++r)
#pragma unroll
                for (int n = 0; n < 3; ++n) {
                    acc[qg * 4 + r][n] = __builtin_amdgcn_mfma_f32_16x16x32_bf16(
                        af[r][0], bn[n][0], acc[qg * 4 + r][n], 0, 0, 0);
                    acc[qg * 4 + r][n] = __builtin_amdgcn_mfma_f32_16x16x32_bf16(
                        af[r][1], bn[n][1], acc[qg * 4 + r][n], 0, 0, 0);
                }
            __builtin_amdgcn_s_setprio(0);
            if (ph == 1) {
                if (!last) asm volatile("s_waitcnt vmcnt(3)" ::: "memory");
                else       asm volatile("s_waitcnt vmcnt(0)" ::: "memory");
            }
            if (ph == 3 && !last)
                asm volatile("s_waitcnt vmcnt(3)" ::: "memory");
            __builtin_amdgcn_s_barrier();
        }
    }

    // fused QKV epilogue (mt-outer)
    int qidxv[3]; int ncolv[3]; float bvv[3];
#pragma unroll
    for (int nt = 0; nt < 3; ++nt) {
        const int col = n0 + wc * 48 + nt * 16 + l15;
        qidxv[nt] = col >> 10;                 // wave-uniform per nt
        ncolv[nt] = col & (D_ - 1);
        bvv[nt] = (qidxv[nt] == 0) ? b0[ncolv[nt]] * cscale
                : (qidxv[nt] == 1) ? b1[ncolv[nt]] : b2[ncolv[nt]];
    }
#pragma unroll
    for (int mt = 0; mt < 8; ++mt) {
        const int rbase = m0 + wr * 128 + mt * 16 + quad * 4;
#pragma unroll
        for (int r2 = 0; r2 < 4; ++r2) {
#pragma unroll
            for (int nt = 0; nt < 3; ++nt) {
                if (qidxv[nt] == 2) continue;
                u16* dst = (qidxv[nt] == 0) ? Qo : Ko;
                dst[(size_t)(rbase + r2) * D_ + ncolv[nt]] =
                    f2b(acc[mt][nt][r2] + bvv[nt]);
            }
        }
#pragma unroll
        for (int nt = 0; nt < 3; ++nt) {       // Vt layout [B][H][HD][S]
            if (qidxv[nt] != 2) continue;
            const int bidx = rbase >> 11, s = rbase & (S_ - 1);
            const int hh = ncolv[nt] >> 6, hd = ncolv[nt] & 63;
            u16x4 pk{f2b(acc[mt][nt][0] + bvv[nt]), f2b(acc[mt][nt][1] + bvv[nt]),
                     f2b(acc[mt][nt][2] + bvv[nt]), f2b(acc[mt][nt][3] + bvv[nt])};
            *(u16x4*)(Vto + (((size_t)(bidx * H_ + hh)) * HD_ + hd) * S_ + s) = pk;
        }
    }
}

// ---------------------------------------------------------------------------
// GEMM core (m97 structure, BK=64, XOR-swizzled LDS): C = A @ W + bias.
// MODE 1: fp32 out [M,N]. (Output projection, N=1024 -> 512 blocks @128^2.)
// ---------------------------------------------------------------------------
#define BM 128
#define BN 128
#define BK 64

template <int MODE>
__global__ __launch_bounds__(256) void gemm_core(
    const u16* __restrict__ A, const u16* __restrict__ Bt,
    const float* __restrict__ b0, const float* __restrict__ b1,
    const float* __restrict__ b2, float cscale,
    void* __restrict__ O0, void* __restrict__ O1, void* __restrict__ O2,
    int M, int N, int K)
{
    __shared__ __align__(16) u16 As[BM * BK];   // 16 KB
    __shared__ __align__(16) u16 Bs[BN * BK];   // 16 KB

    const int tid  = threadIdx.x;
    const int lane = tid & 63;
    const int wave = tid >> 6;
    const int wr = wave >> 1, wc = wave & 1;
    const int l15 = lane & 15, quad = lane >> 4;
    const int m0 = blockIdx.x * BM, n0 = blockIdx.y * BN;
    const int r8 = lane >> 3;
    const int csw = ((lane & 7) ^ r8) * 8;      // swizzled global chunk

    f32x4 acc[4][4] = {};

    for (int k0 = 0; k0 < K; k0 += BK) {
#pragma unroll
        for (int i = 0; i < 4; ++i) {
            const int row = wave * 32 + i * 8 + r8;
            gl_lds16(A  + (size_t)(m0 + row) * K + k0 + csw,
                     As + (wave * 32 + i * 8) * BK);
            gl_lds16(Bt + (size_t)(n0 + row) * K + k0 + csw,
                     Bs + (wave * 32 + i * 8) * BK);
        }
        __syncthreads();
        bf16x8 af[4][2], bfr[4][2];
#pragma unroll
        for (int t = 0; t < 4; ++t) {
            const u16* ap = As + (wr * 64 + t * 16 + l15) * BK;
            const u16* bp = Bs + (wc * 64 + t * 16 + l15) * BK;
            const int s7 = l15 & 7;
            af[t][0]  = *(const bf16x8*)(ap + ((quad    ) ^ s7) * 8);
            af[t][1]  = *(const bf16x8*)(ap + ((quad + 4) ^ s7) * 8);
            bfr[t][0] = *(const bf16x8*)(bp + ((quad    ) ^ s7) * 8);
            bfr[t][1] = *(const bf16x8*)(bp + ((quad + 4) ^ s7) * 8);
        }
#pragma unroll
        for (int mt = 0; mt < 4; ++mt)
#pragma unroll
            for (int nt = 0; nt < 4; ++nt) {
                acc[mt][nt] = __builtin_amdgcn_mfma_f32_16x16x32_bf16(
                    af[mt][0], bfr[nt][0], acc[mt][nt], 0, 0, 0);
                acc[mt][nt] = __builtin_amdgcn_mfma_f32_16x16x32_bf16(
                    af[mt][1], bfr[nt][1], acc[mt][nt], 0, 0, 0);
            }
        __syncthreads();
    }

#pragma unroll
    for (int nt = 0; nt < 4; ++nt) {
        const int col = n0 + wc * 64 + nt * 16 + l15;
        if constexpr (MODE == 1) {
            const float bv = b0[col];
#pragma unroll
            for (int mt = 0; mt < 4; ++mt) {
                const int rbase = m0 + wr * 64 + mt * 16 + quad * 4;
#pragma unroll
                for (int r2 = 0; r2 < 4; ++r2)
                    ((float*)O0)[(size_t)(rbase + r2) * N + col] =
                        acc[mt][nt][r2] + bv;
            }
        } else {
            const int qidx = col >> 10, ncol = col & (D_ - 1);
            const float bv = (qidx == 0) ? b0[ncol] * cscale
                           : (qidx == 1) ? b1[ncol] : b2[ncol];
#pragma unroll
            for (int mt = 0; mt < 4; ++mt) {
                const int rbase = m0 + wr * 64 + mt * 16 + quad * 4;
                if (qidx == 2) {   // Vt layout [B][H][HD][S]
                    const int bidx = rbase >> 11, s = rbase & (S_ - 1);
                    const int hh = ncol >> 6, hd = ncol & 63;
                    u16x4 pk{f2b(acc[mt][nt][0] + bv), f2b(acc[mt][nt][1] + bv),
                             f2b(acc[mt][nt][2] + bv), f2b(acc[mt][nt][3] + bv)};
                    *(u16x4*)((u16*)O2 +
                        (((size_t)(bidx * H_ + hh)) * HD_ + hd) * S_ + s) = pk;
                } else {
                    u16* dst = (qidx == 0) ? (u16*)O0 : (u16*)O1;
#pragma unroll
                    for (int r2 = 0; r2 < 4; ++r2)
                        dst[(size_t)(rbase + r2) * D_ + ncol] =
                            f2b(acc[mt][nt][r2] + bv);
                }
            }
        }
    }
}

// ---------------------------------------------------------------------------
// Causal flash attention, MFMA, shuffle P-transform.
// Q pre-scaled by log2(e)/8. K [B,S,H,HD], Vt [B,H,HD,S].
// Block = q-tile pair {j, 31-j}, j=0..15 -> 1024 blocks, 33 passes/block
// (balanced); grid (bh, j): all 16 j-blocks of a head land on one XCD
// (64 bh % 8), so per-XCD L2 holds its 8 heads' K+V (8 x 512KB = 4MB).
//
// r6: K/V LDS staging REMOVED (m169 precedent: staging L2-fit data is pure
// overhead). r5 arithmetic: 16 ds_read_b128 + 16 ds_bpermute + staging
// ds_writes ~= 68us of serialized LDS-pipe time per CU = the whole kernel.
// Fragments now load directly from global (L2/L1-resident); the XOR-swizzle
// algebra collapses to plain addresses (chunk (quad^s7)^s7 = quad). No
// barriers remain in the main loop; dual iterations re-read the same 32KB
// tile back-to-back -> L1-resident. LDS = 8KB epilogue scratch only.
// ---------------------------------------------------------------------------
__global__ __launch_bounds__(256, 4) void attn_mfma_k(
    const u16* __restrict__ Qm, const u16* __restrict__ Km,
    const u16* __restrict__ Vtg, u16* __restrict__ Om)
{
    __shared__ __align__(16) u16 Ps[4][16 * 64];     // 8 KB (epilogue only)

    const int tid  = threadIdx.x;
    const int lane = tid & 63;
    const int wave = tid >> 6;
    const int l15  = lane & 15;
    const int quad = lane >> 4;
    const int s7   = l15 & 7;
    const int bh = blockIdx.x, b = bh >> 4, h = bh & (H_ - 1);
    const int j  = blockIdx.y;                 // 0..15
    const int dg0 = j, dg1 = 31 - j;

    const u16* Qg = Qm + (size_t)b * S_ * D_ + h * HD_;
    const u16* Kg = Km + (size_t)b * S_ * D_ + h * HD_;
    const u16* Vg = Vtg + ((size_t)(b * H_ + h)) * HD_ * S_;

    bf16x8 qf0[2], qf1[2];
    {
        const u16* qp = Qg + (size_t)(dg0 * 64 + wave * 16 + l15) * D_ + quad * 8;
        qf0[0] = *(const bf16x8*)qp; qf0[1] = *(const bf16x8*)(qp + 32);
        qp = Qg + (size_t)(dg1 * 64 + wave * 16 + l15) * D_ + quad * 8;
        qf1[0] = *(const bf16x8*)qp; qf1[1] = *(const bf16x8*)(qp + 32);
    }

    f32x4 of0[4] = {}, of1[4] = {};
    float lacc0 = 0.f, lacc1 = 0.f;
    const int qloc = wave * 16 + l15;
    const int srcA = l15 + ((quad & 1) << 5);  // shuffle source lanes
    const int srcB = srcA + 16;

    auto pass = [&](const bf16x8 (&q)[2], f32x4 (&o)[4], float& la,
                    bool domask, int t) {
        // S^T = K.Q^T -- K fragments direct from global (L2/L1-resident)
        f32x4 sf[4];
        const u16* kp0 = Kg + (size_t)(t * 64 + l15) * D_ + quad * 8;
#pragma unroll
        for (int kt = 0; kt < 4; ++kt) {
            const u16* kp = kp0 + (size_t)(kt * 16) * D_;
            bf16x8 k0 = *(const bf16x8*)kp;
            bf16x8 k1 = *(const bf16x8*)(kp + 32);
            f32x4 a = {};
            a = __builtin_amdgcn_mfma_f32_16x16x32_bf16(k0, q[0], a, 0, 0, 0);
            a = __builtin_amdgcn_mfma_f32_16x16x32_bf16(k1, q[1], a, 0, 0, 0);
            sf[kt] = a;
        }
        // exp2 + pack P into w[kt][h] = keys kt*16+quad*4+{2h,2h+1}
        unsigned int w[4][2];
        float ls = 0.f;
        if (domask) {
#pragma unroll
            for (int kt = 0; kt < 4; ++kt)
#pragma unroll
                for (int hh = 0; hh < 2; ++hh) {
                    float v0 = sf[kt][2 * hh], v1 = sf[kt][2 * hh + 1];
                    if (kt * 16 + quad * 4 + 2 * hh     > qloc) v0 = -INFINITY;
                    if (kt * 16 + quad * 4 + 2 * hh + 1 > qloc) v1 = -INFINITY;
                    float p0 = __builtin_amdgcn_exp2f(v0);
                    float p1 = __builtin_amdgcn_exp2f(v1);
                    ls += p0 + p1;
                    w[kt][hh] = (__builtin_bit_cast(unsigned int, p0) >> 16) |
                                (__builtin_bit_cast(unsigned int, p1) & 0xFFFF0000u);
                }
        } else {
#pragma unroll
            for (int kt = 0; kt < 4; ++kt)
#pragma unroll
                for (int hh = 0; hh < 2; ++hh) {
                    float p0 = __builtin_amdgcn_exp2f(sf[kt][2 * hh]);
                    float p1 = __builtin_amdgcn_exp2f(sf[kt][2 * hh + 1]);
                    ls += p0 + p1;
                    w[kt][hh] = (__builtin_bit_cast(unsigned int, p0) >> 16) |
                                (__builtin_bit_cast(unsigned int, p1) & 0xFFFF0000u);
                }
        }
        la += ls;
        // C-layout -> B-layout via shuffles (no LDS)
        const bool hi = (quad & 2) != 0;
        i32x4 f0, f1;
        {
            int a0, a1;
            a0 = __shfl((int)w[0][0], srcA); a1 = __shfl((int)w[1][0], srcA);
            f0.x = hi ? a1 : a0;
            a0 = __shfl((int)w[0][1], srcA); a1 = __shfl((int)w[1][1], srcA);
            f0.y = hi ? a1 : a0;
            a0 = __shfl((int)w[0][0], srcB); a1 = __shfl((int)w[1][0], srcB);
            f0.z = hi ? a1 : a0;
            a0 = __shfl((int)w[0][1], srcB); a1 = __shfl((int)w[1][1], srcB);
            f0.w = hi ? a1 : a0;
            a0 = __shfl((int)w[2][0], srcA); a1 = __shfl((int)w[3][0], srcA);
            f1.x = hi ? a1 : a0;
            a0 = __shfl((int)w[2][1], srcA); a1 = __shfl((int)w[3][1], srcA);
            f1.y = hi ? a1 : a0;
            a0 = __shfl((int)w[2][0], srcB); a1 = __shfl((int)w[3][0], srcB);
            f1.z = hi ? a1 : a0;
            a0 = __shfl((int)w[2][1], srcB); a1 = __shfl((int)w[3][1], srcB);
            f1.w = hi ? a1 : a0;
        }
        bf16x8 pf0 = __builtin_bit_cast(bf16x8, f0);
        bf16x8 pf1 = __builtin_bit_cast(bf16x8, f1);
        // ctx^T += Vt.P^T -- V fragments direct from global
#pragma unroll
        for (int dt = 0; dt < 4; ++dt) {
            const u16* vp = Vg + (size_t)(dt * 16 + l15) * S_ + t * 64 + quad * 8;
            bf16x8 v0 = *(const bf16x8*)vp;
            bf16x8 v1 = *(const bf16x8*)(vp + 32);
            o[dt] = __builtin_amdgcn_mfma_f32_16x16x32_bf16(v0, pf0, o[dt], 0, 0, 0);
            o[dt] = __builtin_amdgcn_mfma_f32_16x16x32_bf16(v1, pf1, o[dt], 0, 0, 0);
        }
    };

    const int T = 32 - j;
    for (int t = 0; t < T; ++t) {
        if (t <= dg0) pass(qf0, of0, lacc0, t == dg0, t);
        pass(qf1, of1, lacc1, t == dg1, t);    // runs every iteration
    }

    u16* pw = Ps[wave];
    auto epi = [&](const f32x4 (&o)[4], float la, int dgq) {
        float ls = la;
        ls += __shfl_xor(ls, 16);
        ls += __shfl_xor(ls, 32);
        const float inv = 1.f / ls;
#pragma unroll
        for (int dt = 0; dt < 4; ++dt) {
            const int g = dt * 16 + quad * 4;
            const int pos = ((g >> 3) ^ s7) * 8 + (g & 7);
            *(u16x4*)(pw + l15 * 64 + pos) =
                u16x4{f2b(o[dt][0] * inv), f2b(o[dt][1] * inv),
                      f2b(o[dt][2] * inv), f2b(o[dt][3] * inv)};
        }
        const int r  = lane >> 2;
        const int cp = lane & 3;
        u16x8 o0 = *(const u16x8*)(pw + r * 64 + ((2 * cp    ) ^ (r & 7)) * 8);
        u16x8 o1 = *(const u16x8*)(pw + r * 64 + ((2 * cp + 1) ^ (r & 7)) * 8);
        u16* op = Om + ((size_t)(b * S_ + dgq * 64 + wave * 16 + r)) * D_ + h * 64 + cp * 16;
        *(u16x8*)op = o0;
        *(u16x8*)(op + 8) = o1;
    };
    epi(of0, lacc0, dg0);
    epi(of1, lacc1, dg1);
}

// ---------------------------------------------------------------------------
extern "C" void kernel_launch(void* const* d_in, const int* in_sizes, int n_in,
                              void* d_out, int out_size, void* d_ws, size_t ws_size,
                              hipStream_t stream)
{
    (void)in_sizes; (void)n_in; (void)out_size; (void)ws_size;
    const float* x  = (const float*)d_in[0];
    const float* Wq = (const float*)d_in[1];
    const float* bq = (const float*)d_in[2];
    const float* Wk = (const float*)d_in[3];
    const float* bk = (const float*)d_in[4];
    const float* Wv = (const float*)d_in[5];
    const float* bv = (const float*)d_in[6];
    const float* Wo = (const float*)d_in[7];
    const float* bo = (const float*)d_in[8];

    const float cscale = 0.18033688011112042f;  // log2(e)/sqrt(64)

    u16* ws = (u16*)d_ws;
    const size_t MD = (size_t)M_ * D_;
    const size_t DD = (size_t)D_ * D_;
    u16* xb    = ws;            // bf16 [M, D]
    u16* Qb    = xb + MD;       // bf16 [B,S,H,HD], pre-scaled
    u16* Kb    = Qb + MD;       // bf16 [B,S,H,HD]
    u16* Vtb   = Kb + MD;       // bf16 [B,H,HD,S]
    u16* Cb    = Vtb + MD;      // ctx bf16 [M, D]
    u16* WqkvT = Cb + MD;       // bf16 [3072, 1024] (Q section pre-scaled)
    u16* WoT   = WqkvT + 3 * DD;

    cvt_k<<<M_ * D_ / 2048, 256, 0, stream>>>(x, xb);

    transpose4_k<<<dim3(D_ / 32, D_ / 32, 4), 256, 0, stream>>>(
        Wq, Wk, Wv, Wo, WqkvT, WoT, cscale);

    gemm_qkv256<<<dim3(M_ / QBM, N3_ / QBN), 512, 0, stream>>>(
        xb, WqkvT, bq, bk, bv, cscale, Qb, Kb, Vtb, M_, N3_, D_);

    attn_mfma_k<<<dim3(B_ * H_, 16), 256, 0, stream>>>(Qb, Kb, Vtb, Cb);

    gemm_core<1><<<dim3(M_ / BM, D_ / BN), 256, 0, stream>>>(
        Cb, WoT, bo, nullptr, nullptr, 1.0f, d_out, nullptr, nullptr, M_, D_, D_);
}

// Round 7
// 267.411 us; speedup vs baseline: 1.6379x; 1.6379x over previous
//
#include <hip/hip_runtime.h>
#include <hip/hip_bf16.h>

// Problem constants
#define B_   4
#define S_   2048
#define H_   16
#define HD_  64
#define D_   1024
#define M_   (B_ * S_)   // 8192 rows
#define N3_  3072

typedef unsigned short u16;
typedef __bf16 bf16x8 __attribute__((ext_vector_type(8)));
typedef float  f32x4  __attribute__((ext_vector_type(4)));
typedef int    i32x4  __attribute__((ext_vector_type(4)));
typedef unsigned short u16x8 __attribute__((ext_vector_type(8)));
typedef unsigned short u16x4 __attribute__((ext_vector_type(4)));

__device__ __forceinline__ float b2f(u16 u) {
    unsigned int x = ((unsigned int)u) << 16;
    return __builtin_bit_cast(float, x);
}
__device__ __forceinline__ u16 f2b(float f) {          // RNE
    unsigned int x = __builtin_bit_cast(unsigned int, f);
    x += 0x7fffu + ((x >> 16) & 1u);
    return (u16)(x >> 16);
}

// async global->LDS, 16B/lane; LDS dest = wave-uniform base + lane*16
typedef const __attribute__((address_space(1))) unsigned int* gas_u32p;
typedef __attribute__((address_space(3))) unsigned int* las_u32p;
__device__ __forceinline__ void gl_lds16(const u16* g, u16* lds_base) {
    __builtin_amdgcn_global_load_lds((gas_u32p)g, (las_u32p)lds_base, 16, 0, 0);
}

// ---------------------------------------------------------------------------
// x fp32 -> bf16, flat
// ---------------------------------------------------------------------------
__global__ __launch_bounds__(256) void cvt_k(const float* __restrict__ in,
                                             u16* __restrict__ out) {
    size_t i = ((size_t)blockIdx.x * 256 + threadIdx.x) * 8;
    float4 a = *(const float4*)(in + i);
    float4 b = *(const float4*)(in + i + 4);
    *(u16x8*)(out + i) = u16x8{f2b(a.x), f2b(a.y), f2b(a.z), f2b(a.w),
                               f2b(b.x), f2b(b.y), f2b(b.z), f2b(b.w)};
}

// ---------------------------------------------------------------------------
// 4 weight transposes fused: z in {0,1,2}: Wq/Wk/Wv -> WqkvT sections
// (z=0 scaled by cscale); z=3: Wo -> WoT.
// ---------------------------------------------------------------------------
__global__ __launch_bounds__(256) void transpose4_k(
    const float* __restrict__ w0, const float* __restrict__ w1,
    const float* __restrict__ w2, const float* __restrict__ w3,
    u16* __restrict__ oqkv, u16* __restrict__ owo, float scale0) {
    __shared__ u16 t[32][33];
    const int z = blockIdx.z;
    const float* in = (z == 0) ? w0 : (z == 1) ? w1 : (z == 2) ? w2 : w3;
    u16* out = (z < 3) ? oqkv + (size_t)z * D_ * D_ : owo;
    const float sc = (z == 0) ? scale0 : 1.0f;
    const int x0 = blockIdx.x * 32, y0 = blockIdx.y * 32;
    const int tx = threadIdx.x & 31, ty = threadIdx.x >> 5;  // 32 x 8
#pragma unroll
    for (int i = 0; i < 32; i += 8)
        t[ty + i][tx] = f2b(in[(size_t)(y0 + ty + i) * D_ + x0 + tx] * sc);
    __syncthreads();
#pragma unroll
    for (int i = 0; i < 32; i += 8)
        out[(size_t)(x0 + ty + i) * D_ + y0 + tx] = t[tx][ty + i];
}

// ---------------------------------------------------------------------------
// QKV GEMM: 256x192 tile, BK=64, 8 waves (2Mx4N), 4-phase schedule with
// counted vmcnt + setprio. XOR-8 chunk swizzle. Grid 32x16 = 512 blocks.
// (Held from r3: three QKV structures converged at ~620-630 TF, limited by
// barrier-aligned LDS-read burst / MFMA burst serialization.)
// ---------------------------------------------------------------------------
#define QBM 256
#define QBN 192
#define QBK 64

__global__ __launch_bounds__(512, 2) void gemm_qkv256(
    const u16* __restrict__ A, const u16* __restrict__ Bt,
    const float* __restrict__ b0, const float* __restrict__ b1,
    const float* __restrict__ b2, float cscale,
    u16* __restrict__ Qo, u16* __restrict__ Ko, u16* __restrict__ Vto,
    int M, int N, int K)
{
    __shared__ __align__(16) u16 As[2][QBM * QBK];   // 64 KB
    __shared__ __align__(16) u16 Bs[2][QBN * QBK];   // 48 KB

    const int tid  = threadIdx.x;
    const int lane = tid & 63;
    const int wave = tid >> 6;                 // 0..7
    const int wr = wave >> 2, wc = wave & 3;   // 2M x 4N
    const int l15 = lane & 15, quad = lane >> 4, s7 = l15 & 7;
    const int r8  = lane >> 3;
    const int csw = ((lane & 7) ^ r8) * 8;     // swizzled global chunk
    const int m0 = blockIdx.x * QBM, n0 = blockIdx.y * QBN;
    (void)M; (void)N;

    const u16* Ag = A  + (size_t)(m0 + wave * 8 + r8) * K + csw;
    const u16* Bg = Bt + (size_t)(n0 + wave * 8 + r8) * K + csw;
    u16* AsW = &As[0][0] + wave * 8 * QBK;
    u16* BsW = &Bs[0][0] + wave * 8 * QBK;
    const size_t rowK64 = (size_t)64 * K;      // 64-row stride (precomputed)

    // stage one 8KB unit (64 rows x 64 cols) = 1 gl_lds per thread
    auto stgA = [&](int buf, int u, int kt) {
        gl_lds16(Ag + (size_t)u * rowK64 + kt * QBK,
                 AsW + buf * (QBM * QBK) + u * 64 * QBK);
    };
    auto stgB = [&](int buf, int u, int kt) {
        gl_lds16(Bg + (size_t)u * rowK64 + kt * QBK,
                 BsW + buf * (QBN * QBK) + u * 64 * QBK);
    };

    f32x4 acc[8][3] = {};

    // prologue: tile0 A+B -> buf0, tile1 B -> buf1 (10 units)
    stgA(0, 0, 0); stgA(0, 1, 0); stgA(0, 2, 0); stgA(0, 3, 0);
    stgB(0, 0, 0); stgB(0, 1, 0); stgB(0, 2, 0);
    stgB(1, 0, 1); stgB(1, 1, 1); stgB(1, 2, 1);
    asm volatile("s_waitcnt vmcnt(3)" ::: "memory");   // buf0 landed
    __builtin_amdgcn_s_barrier();

    const int NIT = K / (2 * QBK);   // 8 iterations, 2 K-tiles each
    for (int it = 0; it < NIT; ++it) {
        const bool last = (it == NIT - 1);
        const int t1 = 2 * it + 1, t2 = 2 * it + 2, t3 = 2 * it + 3;
        bf16x8 bn[3][2];
#pragma unroll
        for (int ph = 0; ph < 4; ++ph) {
            const int hb = ph >> 1;            // buffer select
            const int qg = ph & 1;             // q-group (acc rows 4qg..4qg+3)
            const u16* as = &As[hb][0];
            const u16* bs = &Bs[hb][0];
            if (qg == 0) {
#pragma unroll
                for (int n = 0; n < 3; ++n) {
                    const u16* bp = bs + (wc * 48 + n * 16 + l15) * QBK;
                    bn[n][0] = *(const bf16x8*)(bp + ((quad    ) ^ s7) * 8);
                    bn[n][1] = *(const bf16x8*)(bp + ((quad + 4) ^ s7) * 8);
                }
            }
            bf16x8 af[4][2];
#pragma unroll
            for (int r = 0; r < 4; ++r) {
                const u16* ap = as + (wr * 128 + (qg * 4 + r) * 16 + l15) * QBK;
                af[r][0] = *(const bf16x8*)(ap + ((quad    ) ^ s7) * 8);
                af[r][1] = *(const bf16x8*)(ap + ((quad + 4) ^ s7) * 8);
            }
            if (ph == 0) { stgA(1, 0, t1); stgA(1, 1, t1);
                           stgA(1, 2, t1); stgA(1, 3, t1); }
            if (!last) {
                if (ph == 1) { stgB(0, 0, t2); stgB(0, 1, t2); stgB(0, 2, t2); }
                if (ph == 2) { stgA(0, 0, t2); stgA(0, 1, t2);
                               stgA(0, 2, t2); stgA(0, 3, t2); }
                if (ph == 3) { stgB(1, 0, t3); stgB(1, 1, t3); stgB(1, 2, t3); }
            }
            __builtin_amdgcn_s_barrier();
            asm volatile("s_waitcnt lgkmcnt(0)" ::: "memory");
            __builtin_amdgcn_sched_barrier(0);
            __builtin_amdgcn_s_setprio(1);
#pragma unroll
            for (int r = 0; r < 4; ++r)
#pragma unroll
                for (int n = 0; n < 3; ++n) {
                    acc[qg * 4 + r][n] = __builtin_amdgcn_mfma_f32_16x16x32_bf16(
                        af[r][0], bn[n][0], acc[qg * 4 + r][n], 0, 0, 0);
                    acc[qg * 4 + r][n] = __builtin_amdgcn_mfma_f32_16x16x32_bf16(
                        af[r][1], bn[n][1], acc[qg * 4 + r][n], 0, 0, 0);
                }
            __builtin_amdgcn_s_setprio(0);
            if (ph == 1) {
                if (!last) asm volatile("s_waitcnt vmcnt(3)" ::: "memory");
                else       asm volatile("s_waitcnt vmcnt(0)" ::: "memory");
            }
            if (ph == 3 && !last)
                asm volatile("s_waitcnt vmcnt(3)" ::: "memory");
            __builtin_amdgcn_s_barrier();
        }
    }

    // fused QKV epilogue (mt-outer)
    int qidxv[3]; int ncolv[3]; float bvv[3];
#pragma unroll
    for (int nt = 0; nt < 3; ++nt) {
        const int col = n0 + wc * 48 + nt * 16 + l15;
        qidxv[nt] = col >> 10;                 // wave-uniform per nt
        ncolv[nt] = col & (D_ - 1);
        bvv[nt] = (qidxv[nt] == 0) ? b0[ncolv[nt]] * cscale
                : (qidxv[nt] == 1) ? b1[ncolv[nt]] : b2[ncolv[nt]];
    }
#pragma unroll
    for (int mt = 0; mt < 8; ++mt) {
        const int rbase = m0 + wr * 128 + mt * 16 + quad * 4;
#pragma unroll
        for (int r2 = 0; r2 < 4; ++r2) {
#pragma unroll
            for (int nt = 0; nt < 3; ++nt) {
                if (qidxv[nt] == 2) continue;
                u16* dst = (qidxv[nt] == 0) ? Qo : Ko;
                dst[(size_t)(rbase + r2) * D_ + ncolv[nt]] =
                    f2b(acc[mt][nt][r2] + bvv[nt]);
            }
        }
#pragma unroll
        for (int nt = 0; nt < 3; ++nt) {       // Vt layout [B][H][HD][S]
            if (qidxv[nt] != 2) continue;
            const int bidx = rbase >> 11, s = rbase & (S_ - 1);
            const int hh = ncolv[nt] >> 6, hd = ncolv[nt] & 63;
            u16x4 pk{f2b(acc[mt][nt][0] + bvv[nt]), f2b(acc[mt][nt][1] + bvv[nt]),
                     f2b(acc[mt][nt][2] + bvv[nt]), f2b(acc[mt][nt][3] + bvv[nt])};
            *(u16x4*)(Vto + (((size_t)(bidx * H_ + hh)) * HD_ + hd) * S_ + s) = pk;
        }
    }
}

// ---------------------------------------------------------------------------
// GEMM core (m97 structure, BK=64, XOR-swizzled LDS): C = A @ W + bias.
// MODE 1: fp32 out [M,N]. (Output projection, N=1024 -> 512 blocks @128^2.)
// ---------------------------------------------------------------------------
#define BM 128
#define BN 128
#define BK 64

template <int MODE>
__global__ __launch_bounds__(256) void gemm_core(
    const u16* __restrict__ A, const u16* __restrict__ Bt,
    const float* __restrict__ b0, const float* __restrict__ b1,
    const float* __restrict__ b2, float cscale,
    void* __restrict__ O0, void* __restrict__ O1, void* __restrict__ O2,
    int M, int N, int K)
{
    __shared__ __align__(16) u16 As[BM * BK];   // 16 KB
    __shared__ __align__(16) u16 Bs[BN * BK];   // 16 KB

    const int tid  = threadIdx.x;
    const int lane = tid & 63;
    const int wave = tid >> 6;
    const int wr = wave >> 1, wc = wave & 1;
    const int l15 = lane & 15, quad = lane >> 4;
    const int m0 = blockIdx.x * BM, n0 = blockIdx.y * BN;
    const int r8 = lane >> 3;
    const int csw = ((lane & 7) ^ r8) * 8;      // swizzled global chunk

    f32x4 acc[4][4] = {};

    for (int k0 = 0; k0 < K; k0 += BK) {
#pragma unroll
        for (int i = 0; i < 4; ++i) {
            const int row = wave * 32 + i * 8 + r8;
            gl_lds16(A  + (size_t)(m0 + row) * K + k0 + csw,
                     As + (wave * 32 + i * 8) * BK);
            gl_lds16(Bt + (size_t)(n0 + row) * K + k0 + csw,
                     Bs + (wave * 32 + i * 8) * BK);
        }
        __syncthreads();
        bf16x8 af[4][2], bfr[4][2];
#pragma unroll
        for (int t = 0; t < 4; ++t) {
            const u16* ap = As + (wr * 64 + t * 16 + l15) * BK;
            const u16* bp = Bs + (wc * 64 + t * 16 + l15) * BK;
            const int s7 = l15 & 7;
            af[t][0]  = *(const bf16x8*)(ap + ((quad    ) ^ s7) * 8);
            af[t][1]  = *(const bf16x8*)(ap + ((quad + 4) ^ s7) * 8);
            bfr[t][0] = *(const bf16x8*)(bp + ((quad    ) ^ s7) * 8);
            bfr[t][1] = *(const bf16x8*)(bp + ((quad + 4) ^ s7) * 8);
        }
#pragma unroll
        for (int mt = 0; mt < 4; ++mt)
#pragma unroll
            for (int nt = 0; nt < 4; ++nt) {
                acc[mt][nt] = __builtin_amdgcn_mfma_f32_16x16x32_bf16(
                    af[mt][0], bfr[nt][0], acc[mt][nt], 0, 0, 0);
                acc[mt][nt] = __builtin_amdgcn_mfma_f32_16x16x32_bf16(
                    af[mt][1], bfr[nt][1], acc[mt][nt], 0, 0, 0);
            }
        __syncthreads();
    }

#pragma unroll
    for (int nt = 0; nt < 4; ++nt) {
        const int col = n0 + wc * 64 + nt * 16 + l15;
        if constexpr (MODE == 1) {
            const float bv = b0[col];
#pragma unroll
            for (int mt = 0; mt < 4; ++mt) {
                const int rbase = m0 + wr * 64 + mt * 16 + quad * 4;
#pragma unroll
                for (int r2 = 0; r2 < 4; ++r2)
                    ((float*)O0)[(size_t)(rbase + r2) * N + col] =
                        acc[mt][nt][r2] + bv;
            }
        } else {
            const int qidx = col >> 10, ncol = col & (D_ - 1);
            const float bv = (qidx == 0) ? b0[ncol] * cscale
                           : (qidx == 1) ? b1[ncol] : b2[ncol];
#pragma unroll
            for (int mt = 0; mt < 4; ++mt) {
                const int rbase = m0 + wr * 64 + mt * 16 + quad * 4;
                if (qidx == 2) {   // Vt layout [B][H][HD][S]
                    const int bidx = rbase >> 11, s = rbase & (S_ - 1);
                    const int hh = ncol >> 6, hd = ncol & 63;
                    u16x4 pk{f2b(acc[mt][nt][0] + bv), f2b(acc[mt][nt][1] + bv),
                             f2b(acc[mt][nt][2] + bv), f2b(acc[mt][nt][3] + bv)};
                    *(u16x4*)((u16*)O2 +
                        (((size_t)(bidx * H_ + hh)) * HD_ + hd) * S_ + s) = pk;
                } else {
                    u16* dst = (qidx == 0) ? (u16*)O0 : (u16*)O1;
#pragma unroll
                    for (int r2 = 0; r2 < 4; ++r2)
                        dst[(size_t)(rbase + r2) * D_ + ncol] =
                            f2b(acc[mt][nt][r2] + bv);
                }
            }
        }
    }
}

// ---------------------------------------------------------------------------
// Causal flash attention, MFMA, LDS-dbuf K/V staging, shuffle P-transform.
// Q pre-scaled by log2(e)/8. K [B,S,H,HD], Vt [B,H,HD,S].
// Block = q-tile pair {j, 31-j}, j=0..15 -> 1024 blocks, 33 passes/block
// (balanced); grid (bh, j) -> XCD = bh%8 (head-local L2).
//
// r7: REVERT to r5 (best-known). r6's direct-global variant removed the
// dbuf prefetch (the kernel's only latency hiding) and multiplied VMEM
// traffic ~8x (per-wave, per-q re-loads) -> latency-bound, 251us, MfmaUtil
// 5.7%. Known facts for future rounds: (1) the kernel is LDS-throughput-
// bound (~290 cyc LDS pipe per pass per wave x 20 waves/CU x 33 passes
// ~= 79us = measured); (2) SQ_LDS_BANK_CONFLICT 4.52M comes ENTIRELY from
// the __shfl ds_bpermutes (unchanged with zero K/V LDS ops in r6);
// (3) register fusion of dual passes spills at the compiler's 64-VGPR
// choice (r4: +24MB scratch WRITE_SIZE).
// ---------------------------------------------------------------------------
__global__ __launch_bounds__(256, 4) void attn_mfma_k(
    const u16* __restrict__ Qm, const u16* __restrict__ Km,
    const u16* __restrict__ Vtg, u16* __restrict__ Om)
{
    __shared__ __align__(16) u16 Kbuf[2][64 * 64];   // 16 KB
    __shared__ __align__(16) u16 Vbuf[2][64 * 64];   // 16 KB
    // epilogue scratch lives in Kbuf[0] (per-wave 16x64 slice, post-barrier)

    const int tid  = threadIdx.x;
    const int lane = tid & 63;
    const int wave = tid >> 6;
    const int l15  = lane & 15;
    const int quad = lane >> 4;
    const int s7   = l15 & 7;
    const int bh = blockIdx.x, b = bh >> 4, h = bh & (H_ - 1);
    const int j  = blockIdx.y;                 // 0..15
    const int dg0 = j, dg1 = 31 - j;

    const u16* Qg = Qm + (size_t)b * S_ * D_ + h * HD_;
    const u16* Kg = Km + (size_t)b * S_ * D_ + h * HD_;
    const u16* Vg = Vtg + ((size_t)(b * H_ + h)) * HD_ * S_;

    bf16x8 qf0[2], qf1[2];
    {
        const u16* qp = Qg + (size_t)(dg0 * 64 + wave * 16 + l15) * D_ + quad * 8;
        qf0[0] = *(const bf16x8*)qp; qf0[1] = *(const bf16x8*)(qp + 32);
        qp = Qg + (size_t)(dg1 * 64 + wave * 16 + l15) * D_ + quad * 8;
        qf1[0] = *(const bf16x8*)qp; qf1[1] = *(const bf16x8*)(qp + 32);
    }

    f32x4 of0[4] = {}, of1[4] = {};
    float lacc0 = 0.f, lacc1 = 0.f;
    const int qloc = wave * 16 + l15;
    const int r8 = lane >> 3;
    const int csw = ((lane & 7) ^ r8) * 8;     // swizzled global chunk
    const int srcA = l15 + ((quad & 1) << 5);  // shuffle source lanes
    const int srcB = srcA + 16;

    auto stage = [&](int t, int bsel) {
        u16* kb = Kbuf[bsel];
        u16* vb = Vbuf[bsel];
#pragma unroll
        for (int i = 0; i < 2; ++i) {
            const int row = wave * 16 + i * 8 + r8;
            gl_lds16(Kg + (size_t)(t * 64 + row) * D_ + csw,
                     kb + (wave * 16 + i * 8) * 64);
            gl_lds16(Vg + (size_t)row * S_ + t * 64 + csw,
                     vb + (wave * 16 + i * 8) * 64);
        }
    };

    auto pass = [&](const bf16x8 (&q)[2], f32x4 (&o)[4], float& la,
                    bool domask, const u16* kb, const u16* vb) {
        // S^T = K.Q^T (K frags read from LDS at point of use)
        f32x4 sf[4];
#pragma unroll
        for (int kt = 0; kt < 4; ++kt) {
            const u16* kp = kb + (kt * 16 + l15) * 64;
            bf16x8 k0 = *(const bf16x8*)(kp + ((quad    ) ^ s7) * 8);
            bf16x8 k1 = *(const bf16x8*)(kp + ((quad + 4) ^ s7) * 8);
            f32x4 a = {};
            a = __builtin_amdgcn_mfma_f32_16x16x32_bf16(k0, q[0], a, 0, 0, 0);
            a = __builtin_amdgcn_mfma_f32_16x16x32_bf16(k1, q[1], a, 0, 0, 0);
            sf[kt] = a;
        }
        // exp2 + pack P into w[kt][h] = keys kt*16+quad*4+{2h,2h+1}
        unsigned int w[4][2];
        float ls = 0.f;
        if (domask) {
#pragma unroll
            for (int kt = 0; kt < 4; ++kt)
#pragma unroll
                for (int hh = 0; hh < 2; ++hh) {
                    float v0 = sf[kt][2 * hh], v1 = sf[kt][2 * hh + 1];
                    if (kt * 16 + quad * 4 + 2 * hh     > qloc) v0 = -INFINITY;
                    if (kt * 16 + quad * 4 + 2 * hh + 1 > qloc) v1 = -INFINITY;
                    float p0 = __builtin_amdgcn_exp2f(v0);
                    float p1 = __builtin_amdgcn_exp2f(v1);
                    ls += p0 + p1;
                    w[kt][hh] = (__builtin_bit_cast(unsigned int, p0) >> 16) |
                                (__builtin_bit_cast(unsigned int, p1) & 0xFFFF0000u);
                }
        } else {
#pragma unroll
            for (int kt = 0; kt < 4; ++kt)
#pragma unroll
                for (int hh = 0; hh < 2; ++hh) {
                    float p0 = __builtin_amdgcn_exp2f(sf[kt][2 * hh]);
                    float p1 = __builtin_amdgcn_exp2f(sf[kt][2 * hh + 1]);
                    ls += p0 + p1;
                    w[kt][hh] = (__builtin_bit_cast(unsigned int, p0) >> 16) |
                                (__builtin_bit_cast(unsigned int, p1) & 0xFFFF0000u);
                }
        }
        la += ls;
        // C-layout -> B-layout via shuffles (no LDS scratch)
        const bool hi = (quad & 2) != 0;
        i32x4 f0, f1;
        {
            int a0, a1;
            a0 = __shfl((int)w[0][0], srcA); a1 = __shfl((int)w[1][0], srcA);
            f0.x = hi ? a1 : a0;
            a0 = __shfl((int)w[0][1], srcA); a1 = __shfl((int)w[1][1], srcA);
            f0.y = hi ? a1 : a0;
            a0 = __shfl((int)w[0][0], srcB); a1 = __shfl((int)w[1][0], srcB);
            f0.z = hi ? a1 : a0;
            a0 = __shfl((int)w[0][1], srcB); a1 = __shfl((int)w[1][1], srcB);
            f0.w = hi ? a1 : a0;
            a0 = __shfl((int)w[2][0], srcA); a1 = __shfl((int)w[3][0], srcA);
            f1.x = hi ? a1 : a0;
            a0 = __shfl((int)w[2][1], srcA); a1 = __shfl((int)w[3][1], srcA);
            f1.y = hi ? a1 : a0;
            a0 = __shfl((int)w[2][0], srcB); a1 = __shfl((int)w[3][0], srcB);
            f1.z = hi ? a1 : a0;
            a0 = __shfl((int)w[2][1], srcB); a1 = __shfl((int)w[3][1], srcB);
            f1.w = hi ? a1 : a0;
        }
        bf16x8 pf0 = __builtin_bit_cast(bf16x8, f0);
        bf16x8 pf1 = __builtin_bit_cast(bf16x8, f1);
        // ctx^T += Vt.P^T (V frags read from LDS at point of use)
#pragma unroll
        for (int dt = 0; dt < 4; ++dt) {
            const u16* vp = vb + (dt * 16 + l15) * 64;
            bf16x8 v0 = *(const bf16x8*)(vp + ((quad    ) ^ s7) * 8);
            bf16x8 v1 = *(const bf16x8*)(vp + ((quad + 4) ^ s7) * 8);
            o[dt] = __builtin_amdgcn_mfma_f32_16x16x32_bf16(v0, pf0, o[dt], 0, 0, 0);
            o[dt] = __builtin_amdgcn_mfma_f32_16x16x32_bf16(v1, pf1, o[dt], 0, 0, 0);
        }
    };

    const int T = 32 - j;
    stage(0, 0);
    for (int t = 0; t < T; ++t) {
        __syncthreads();                       // buf[t&1] ready (vmcnt drain)
        if (t + 1 < T) stage(t + 1, (t + 1) & 1);
        const u16* kb = Kbuf[t & 1];
        const u16* vb = Vbuf[t & 1];
        if (t <= dg0) pass(qf0, of0, lacc0, t == dg0, kb, vb);
        pass(qf1, of1, lacc1, t == dg1, kb, vb);   // runs every iteration
    }

    // all waves done reading K/V buffers -> reuse Kbuf[0] as epilogue scratch
    __syncthreads();
    u16* pw = &Kbuf[0][0] + wave * 16 * 64;
    auto epi = [&](const f32x4 (&o)[4], float la, int dgq) {
        float ls = la;
        ls += __shfl_xor(ls, 16);
        ls += __shfl_xor(ls, 32);
        const float inv = 1.f / ls;
#pragma unroll
        for (int dt = 0; dt < 4; ++dt) {
            const int g = dt * 16 + quad * 4;
            const int pos = ((g >> 3) ^ s7) * 8 + (g & 7);
            *(u16x4*)(pw + l15 * 64 + pos) =
                u16x4{f2b(o[dt][0] * inv), f2b(o[dt][1] * inv),
                      f2b(o[dt][2] * inv), f2b(o[dt][3] * inv)};
        }
        const int r  = lane >> 2;
        const int cp = lane & 3;
        u16x8 o0 = *(const u16x8*)(pw + r * 64 + ((2 * cp    ) ^ (r & 7)) * 8);
        u16x8 o1 = *(const u16x8*)(pw + r * 64 + ((2 * cp + 1) ^ (r & 7)) * 8);
        u16* op = Om + ((size_t)(b * S_ + dgq * 64 + wave * 16 + r)) * D_ + h * 64 + cp * 16;
        *(u16x8*)op = o0;
        *(u16x8*)(op + 8) = o1;
    };
    epi(of0, lacc0, dg0);
    epi(of1, lacc1, dg1);
}

// ---------------------------------------------------------------------------
extern "C" void kernel_launch(void* const* d_in, const int* in_sizes, int n_in,
                              void* d_out, int out_size, void* d_ws, size_t ws_size,
                              hipStream_t stream)
{
    (void)in_sizes; (void)n_in; (void)out_size; (void)ws_size;
    const float* x  = (const float*)d_in[0];
    const float* Wq = (const float*)d_in[1];
    const float* bq = (const float*)d_in[2];
    const float* Wk = (const float*)d_in[3];
    const float* bk = (const float*)d_in[4];
    const float* Wv = (const float*)d_in[5];
    const float* bv = (const float*)d_in[6];
    const float* Wo = (const float*)d_in[7];
    const float* bo = (const float*)d_in[8];

    const float cscale = 0.18033688011112042f;  // log2(e)/sqrt(64)

    u16* ws = (u16*)d_ws;
    const size_t MD = (size_t)M_ * D_;
    const size_t DD = (size_t)D_ * D_;
    u16* xb    = ws;            // bf16 [M, D]
    u16* Qb    = xb + MD;       // bf16 [B,S,H,HD], pre-scaled
    u16* Kb    = Qb + MD;       // bf16 [B,S,H,HD]
    u16* Vtb   = Kb + MD;       // bf16 [B,H,HD,S]
    u16* Cb    = Vtb + MD;      // ctx bf16 [M, D]
    u16* WqkvT = Cb + MD;       // bf16 [3072, 1024] (Q section pre-scaled)
    u16* WoT   = WqkvT + 3 * DD;

    cvt_k<<<M_ * D_ / 2048, 256, 0, stream>>>(x, xb);

    transpose4_k<<<dim3(D_ / 32, D_ / 32, 4), 256, 0, stream>>>(
        Wq, Wk, Wv, Wo, WqkvT, WoT, cscale);

    gemm_qkv256<<<dim3(M_ / QBM, N3_ / QBN), 512, 0, stream>>>(
        xb, WqkvT, bq, bk, bv, cscale, Qb, Kb, Vtb, M_, N3_, D_);

    attn_mfma_k<<<dim3(B_ * H_, 16), 256, 0, stream>>>(Qb, Kb, Vtb, Cb);

    gemm_core<1><<<dim3(M_ / BM, D_ / BN), 256, 0, stream>>>(
        Cb, WoT, bo, nullptr, nullptr, 1.0f, d_out, nullptr, nullptr, M_, D_, D_);
}

// Round 8
// 251.046 us; speedup vs baseline: 1.7446x; 1.0652x over previous
//
#include <hip/hip_runtime.h>
#include <hip/hip_bf16.h>

// Problem constants
#define B_   4
#define S_   2048
#define H_   16
#define HD_  64
#define D_   1024
#define M_   (B_ * S_)   // 8192 rows
#define N3_  3072

typedef unsigned short u16;
typedef __bf16 bf16x8 __attribute__((ext_vector_type(8)));
typedef float  f32x4  __attribute__((ext_vector_type(4)));
typedef int    i32x4  __attribute__((ext_vector_type(4)));
typedef unsigned int u32x2 __attribute__((ext_vector_type(2)));
typedef unsigned short u16x8 __attribute__((ext_vector_type(8)));
typedef unsigned short u16x4 __attribute__((ext_vector_type(4)));

__device__ __forceinline__ float b2f(u16 u) {
    unsigned int x = ((unsigned int)u) << 16;
    return __builtin_bit_cast(float, x);
}
__device__ __forceinline__ u16 f2b(float f) {          // RNE
    unsigned int x = __builtin_bit_cast(unsigned int, f);
    x += 0x7fffu + ((x >> 16) & 1u);
    return (u16)(x >> 16);
}

// async global->LDS, 16B/lane; LDS dest = wave-uniform base + lane*16
typedef const __attribute__((address_space(1))) unsigned int* gas_u32p;
typedef __attribute__((address_space(3))) unsigned int* las_u32p;
__device__ __forceinline__ void gl_lds16(const u16* g, u16* lds_base) {
    __builtin_amdgcn_global_load_lds((gas_u32p)g, (las_u32p)lds_base, 16, 0, 0);
}

// ---------------------------------------------------------------------------
// x fp32 -> bf16, flat
// ---------------------------------------------------------------------------
__global__ __launch_bounds__(256) void cvt_k(const float* __restrict__ in,
                                             u16* __restrict__ out) {
    size_t i = ((size_t)blockIdx.x * 256 + threadIdx.x) * 8;
    float4 a = *(const float4*)(in + i);
    float4 b = *(const float4*)(in + i + 4);
    *(u16x8*)(out + i) = u16x8{f2b(a.x), f2b(a.y), f2b(a.z), f2b(a.w),
                               f2b(b.x), f2b(b.y), f2b(b.z), f2b(b.w)};
}

// ---------------------------------------------------------------------------
// 4 weight transposes fused: z in {0,1,2}: Wq/Wk/Wv -> WqkvT sections
// (z=0 scaled by cscale); z=3: Wo -> WoT.
// ---------------------------------------------------------------------------
__global__ __launch_bounds__(256) void transpose4_k(
    const float* __restrict__ w0, const float* __restrict__ w1,
    const float* __restrict__ w2, const float* __restrict__ w3,
    u16* __restrict__ oqkv, u16* __restrict__ owo, float scale0) {
    __shared__ u16 t[32][33];
    const int z = blockIdx.z;
    const float* in = (z == 0) ? w0 : (z == 1) ? w1 : (z == 2) ? w2 : w3;
    u16* out = (z < 3) ? oqkv + (size_t)z * D_ * D_ : owo;
    const float sc = (z == 0) ? scale0 : 1.0f;
    const int x0 = blockIdx.x * 32, y0 = blockIdx.y * 32;
    const int tx = threadIdx.x & 31, ty = threadIdx.x >> 5;  // 32 x 8
#pragma unroll
    for (int i = 0; i < 32; i += 8)
        t[ty + i][tx] = f2b(in[(size_t)(y0 + ty + i) * D_ + x0 + tx] * sc);
    __syncthreads();
#pragma unroll
    for (int i = 0; i < 32; i += 8)
        out[(size_t)(x0 + ty + i) * D_ + y0 + tx] = t[tx][ty + i];
}

// ---------------------------------------------------------------------------
// QKV GEMM: 256x192 tile, BK=64, 8 waves (2Mx4N), 4-phase schedule with
// counted vmcnt + setprio. XOR-8 chunk swizzle. Grid 32x16 = 512 blocks.
// (Held from r3: three QKV structures converged at ~620-630 TF, limited by
// barrier-aligned LDS-read burst / MFMA burst serialization.)
// ---------------------------------------------------------------------------
#define QBM 256
#define QBN 192
#define QBK 64

__global__ __launch_bounds__(512, 2) void gemm_qkv256(
    const u16* __restrict__ A, const u16* __restrict__ Bt,
    const float* __restrict__ b0, const float* __restrict__ b1,
    const float* __restrict__ b2, float cscale,
    u16* __restrict__ Qo, u16* __restrict__ Ko, u16* __restrict__ Vto,
    int M, int N, int K)
{
    __shared__ __align__(16) u16 As[2][QBM * QBK];   // 64 KB
    __shared__ __align__(16) u16 Bs[2][QBN * QBK];   // 48 KB

    const int tid  = threadIdx.x;
    const int lane = tid & 63;
    const int wave = tid >> 6;                 // 0..7
    const int wr = wave >> 2, wc = wave & 3;   // 2M x 4N
    const int l15 = lane & 15, quad = lane >> 4, s7 = l15 & 7;
    const int r8  = lane >> 3;
    const int csw = ((lane & 7) ^ r8) * 8;     // swizzled global chunk
    const int m0 = blockIdx.x * QBM, n0 = blockIdx.y * QBN;
    (void)M; (void)N;

    const u16* Ag = A  + (size_t)(m0 + wave * 8 + r8) * K + csw;
    const u16* Bg = Bt + (size_t)(n0 + wave * 8 + r8) * K + csw;
    u16* AsW = &As[0][0] + wave * 8 * QBK;
    u16* BsW = &Bs[0][0] + wave * 8 * QBK;
    const size_t rowK64 = (size_t)64 * K;      // 64-row stride (precomputed)

    // stage one 8KB unit (64 rows x 64 cols) = 1 gl_lds per thread
    auto stgA = [&](int buf, int u, int kt) {
        gl_lds16(Ag + (size_t)u * rowK64 + kt * QBK,
                 AsW + buf * (QBM * QBK) + u * 64 * QBK);
    };
    auto stgB = [&](int buf, int u, int kt) {
        gl_lds16(Bg + (size_t)u * rowK64 + kt * QBK,
                 BsW + buf * (QBN * QBK) + u * 64 * QBK);
    };

    f32x4 acc[8][3] = {};

    // prologue: tile0 A+B -> buf0, tile1 B -> buf1 (10 units)
    stgA(0, 0, 0); stgA(0, 1, 0); stgA(0, 2, 0); stgA(0, 3, 0);
    stgB(0, 0, 0); stgB(0, 1, 0); stgB(0, 2, 0);
    stgB(1, 0, 1); stgB(1, 1, 1); stgB(1, 2, 1);
    asm volatile("s_waitcnt vmcnt(3)" ::: "memory");   // buf0 landed
    __builtin_amdgcn_s_barrier();

    const int NIT = K / (2 * QBK);   // 8 iterations, 2 K-tiles each
    for (int it = 0; it < NIT; ++it) {
        const bool last = (it == NIT - 1);
        const int t1 = 2 * it + 1, t2 = 2 * it + 2, t3 = 2 * it + 3;
        bf16x8 bn[3][2];
#pragma unroll
        for (int ph = 0; ph < 4; ++ph) {
            const int hb = ph >> 1;            // buffer select
            const int qg = ph & 1;             // q-group (acc rows 4qg..4qg+3)
            const u16* as = &As[hb][0];
            const u16* bs = &Bs[hb][0];
            if (qg == 0) {
#pragma unroll
                for (int n = 0; n < 3; ++n) {
                    const u16* bp = bs + (wc * 48 + n * 16 + l15) * QBK;
                    bn[n][0] = *(const bf16x8*)(bp + ((quad    ) ^ s7) * 8);
                    bn[n][1] = *(const bf16x8*)(bp + ((quad + 4) ^ s7) * 8);
                }
            }
            bf16x8 af[4][2];
#pragma unroll
            for (int r = 0; r < 4; ++r) {
                const u16* ap = as + (wr * 128 + (qg * 4 + r) * 16 + l15) * QBK;
                af[r][0] = *(const bf16x8*)(ap + ((quad    ) ^ s7) * 8);
                af[r][1] = *(const bf16x8*)(ap + ((quad + 4) ^ s7) * 8);
            }
            if (ph == 0) { stgA(1, 0, t1); stgA(1, 1, t1);
                           stgA(1, 2, t1); stgA(1, 3, t1); }
            if (!last) {
                if (ph == 1) { stgB(0, 0, t2); stgB(0, 1, t2); stgB(0, 2, t2); }
                if (ph == 2) { stgA(0, 0, t2); stgA(0, 1, t2);
                               stgA(0, 2, t2); stgA(0, 3, t2); }
                if (ph == 3) { stgB(1, 0, t3); stgB(1, 1, t3); stgB(1, 2, t3); }
            }
            __builtin_amdgcn_s_barrier();
            asm volatile("s_waitcnt lgkmcnt(0)" ::: "memory");
            __builtin_amdgcn_sched_barrier(0);
            __builtin_amdgcn_s_setprio(1);
#pragma unroll
            for (int r = 0; r < 4; ++r)
#pragma unroll
                for (int n = 0; n < 3; ++n) {
                    acc[qg * 4 + r][n] = __builtin_amdgcn_mfma_f32_16x16x32_bf16(
                        af[r][0], bn[n][0], acc[qg * 4 + r][n], 0, 0, 0);
                    acc[qg * 4 + r][n] = __builtin_amdgcn_mfma_f32_16x16x32_bf16(
                        af[r][1], bn[n][1], acc[qg * 4 + r][n], 0, 0, 0);
                }
            __builtin_amdgcn_s_setprio(0);
            if (ph == 1) {
                if (!last) asm volatile("s_waitcnt vmcnt(3)" ::: "memory");
                else       asm volatile("s_waitcnt vmcnt(0)" ::: "memory");
            }
            if (ph == 3 && !last)
                asm volatile("s_waitcnt vmcnt(3)" ::: "memory");
            __builtin_amdgcn_s_barrier();
        }
    }

    // fused QKV epilogue (mt-outer)
    int qidxv[3]; int ncolv[3]; float bvv[3];
#pragma unroll
    for (int nt = 0; nt < 3; ++nt) {
        const int col = n0 + wc * 48 + nt * 16 + l15;
        qidxv[nt] = col >> 10;                 // wave-uniform per nt
        ncolv[nt] = col & (D_ - 1);
        bvv[nt] = (qidxv[nt] == 0) ? b0[ncolv[nt]] * cscale
                : (qidxv[nt] == 1) ? b1[ncolv[nt]] : b2[ncolv[nt]];
    }
#pragma unroll
    for (int mt = 0; mt < 8; ++mt) {
        const int rbase = m0 + wr * 128 + mt * 16 + quad * 4;
#pragma unroll
        for (int r2 = 0; r2 < 4; ++r2) {
#pragma unroll
            for (int nt = 0; nt < 3; ++nt) {
                if (qidxv[nt] == 2) continue;
                u16* dst = (qidxv[nt] == 0) ? Qo : Ko;
                dst[(size_t)(rbase + r2) * D_ + ncolv[nt]] =
                    f2b(acc[mt][nt][r2] + bvv[nt]);
            }
        }
#pragma unroll
        for (int nt = 0; nt < 3; ++nt) {       // Vt layout [B][H][HD][S]
            if (qidxv[nt] != 2) continue;
            const int bidx = rbase >> 11, s = rbase & (S_ - 1);
            const int hh = ncolv[nt] >> 6, hd = ncolv[nt] & 63;
            u16x4 pk{f2b(acc[mt][nt][0] + bvv[nt]), f2b(acc[mt][nt][1] + bvv[nt]),
                     f2b(acc[mt][nt][2] + bvv[nt]), f2b(acc[mt][nt][3] + bvv[nt])};
            *(u16x4*)(Vto + (((size_t)(bidx * H_ + hh)) * HD_ + hd) * S_ + s) = pk;
        }
    }
}

// ---------------------------------------------------------------------------
// GEMM core (m97 structure, BK=64, XOR-swizzled LDS): C = A @ W + bias.
// MODE 1: fp32 out [M,N]. (Output projection, N=1024 -> 512 blocks @128^2.)
// ---------------------------------------------------------------------------
#define BM 128
#define BN 128
#define BK 64

template <int MODE>
__global__ __launch_bounds__(256) void gemm_core(
    const u16* __restrict__ A, const u16* __restrict__ Bt,
    const float* __restrict__ b0, const float* __restrict__ b1,
    const float* __restrict__ b2, float cscale,
    void* __restrict__ O0, void* __restrict__ O1, void* __restrict__ O2,
    int M, int N, int K)
{
    __shared__ __align__(16) u16 As[BM * BK];   // 16 KB
    __shared__ __align__(16) u16 Bs[BN * BK];   // 16 KB

    const int tid  = threadIdx.x;
    const int lane = tid & 63;
    const int wave = tid >> 6;
    const int wr = wave >> 1, wc = wave & 1;
    const int l15 = lane & 15, quad = lane >> 4;
    const int m0 = blockIdx.x * BM, n0 = blockIdx.y * BN;
    const int r8 = lane >> 3;
    const int csw = ((lane & 7) ^ r8) * 8;      // swizzled global chunk

    f32x4 acc[4][4] = {};

    for (int k0 = 0; k0 < K; k0 += BK) {
#pragma unroll
        for (int i = 0; i < 4; ++i) {
            const int row = wave * 32 + i * 8 + r8;
            gl_lds16(A  + (size_t)(m0 + row) * K + k0 + csw,
                     As + (wave * 32 + i * 8) * BK);
            gl_lds16(Bt + (size_t)(n0 + row) * K + k0 + csw,
                     Bs + (wave * 32 + i * 8) * BK);
        }
        __syncthreads();
        bf16x8 af[4][2], bfr[4][2];
#pragma unroll
        for (int t = 0; t < 4; ++t) {
            const u16* ap = As + (wr * 64 + t * 16 + l15) * BK;
            const u16* bp = Bs + (wc * 64 + t * 16 + l15) * BK;
            const int s7 = l15 & 7;
            af[t][0]  = *(const bf16x8*)(ap + ((quad    ) ^ s7) * 8);
            af[t][1]  = *(const bf16x8*)(ap + ((quad + 4) ^ s7) * 8);
            bfr[t][0] = *(const bf16x8*)(bp + ((quad    ) ^ s7) * 8);
            bfr[t][1] = *(const bf16x8*)(bp + ((quad + 4) ^ s7) * 8);
        }
#pragma unroll
        for (int mt = 0; mt < 4; ++mt)
#pragma unroll
            for (int nt = 0; nt < 4; ++nt) {
                acc[mt][nt] = __builtin_amdgcn_mfma_f32_16x16x32_bf16(
                    af[mt][0], bfr[nt][0], acc[mt][nt], 0, 0, 0);
                acc[mt][nt] = __builtin_amdgcn_mfma_f32_16x16x32_bf16(
                    af[mt][1], bfr[nt][1], acc[mt][nt], 0, 0, 0);
            }
        __syncthreads();
    }

#pragma unroll
    for (int nt = 0; nt < 4; ++nt) {
        const int col = n0 + wc * 64 + nt * 16 + l15;
        if constexpr (MODE == 1) {
            const float bv = b0[col];
#pragma unroll
            for (int mt = 0; mt < 4; ++mt) {
                const int rbase = m0 + wr * 64 + mt * 16 + quad * 4;
#pragma unroll
                for (int r2 = 0; r2 < 4; ++r2)
                    ((float*)O0)[(size_t)(rbase + r2) * N + col] =
                        acc[mt][nt][r2] + bv;
            }
        } else {
            const int qidx = col >> 10, ncol = col & (D_ - 1);
            const float bv = (qidx == 0) ? b0[ncol] * cscale
                           : (qidx == 1) ? b1[ncol] : b2[ncol];
#pragma unroll
            for (int mt = 0; mt < 4; ++mt) {
                const int rbase = m0 + wr * 64 + mt * 16 + quad * 4;
                if (qidx == 2) {   // Vt layout [B][H][HD][S]
                    const int bidx = rbase >> 11, s = rbase & (S_ - 1);
                    const int hh = ncol >> 6, hd = ncol & 63;
                    u16x4 pk{f2b(acc[mt][nt][0] + bv), f2b(acc[mt][nt][1] + bv),
                             f2b(acc[mt][nt][2] + bv), f2b(acc[mt][nt][3] + bv)};
                    *(u16x4*)((u16*)O2 +
                        (((size_t)(bidx * H_ + hh)) * HD_ + hd) * S_ + s) = pk;
                } else {
                    u16* dst = (qidx == 0) ? (u16*)O0 : (u16*)O1;
#pragma unroll
                    for (int r2 = 0; r2 < 4; ++r2)
                        dst[(size_t)(rbase + r2) * D_ + ncol] =
                            f2b(acc[mt][nt][r2] + bv);
                }
            }
        }
    }
}

// ---------------------------------------------------------------------------
// Causal flash attention, MFMA, LDS-dbuf K/V staging.
// Q pre-scaled by log2(e)/8. K [B,S,H,HD], Vt [B,H,HD,S].
// Block = q-tile pair {j, 31-j}, j=0..15 -> 1024 blocks, 33 passes/block
// (balanced); grid (bh, j) -> XCD = bh%8 (head-local L2).
//
// r8: P-transform (C-layout -> B-layout) moved OFF the LDS pipe: the 16
// __shfl (ds_bpermute, source of ALL 4.52M bank conflicts per r6's control)
// + 8 selects are replaced by 8 VALU ops:
//   (X,Z) = permlane16_swap(permlane32_swap(g0,g1))
// which yields X=[g0@q0,g0@q2,g1@q0,g1@q2], Z=[g0@q1,g0@q3,g1@q1,g1@q3] --
// exactly the old srcA/srcB/hi-select results (verified lane-by-lane).
// Kernel is LDS-throughput-bound (r5/r6 evidence), so removing 16 LDS-pipe
// ops/pass is the direct lever. Same values bit-for-bit.
// ---------------------------------------------------------------------------
__global__ __launch_bounds__(256, 4) void attn_mfma_k(
    const u16* __restrict__ Qm, const u16* __restrict__ Km,
    const u16* __restrict__ Vtg, u16* __restrict__ Om)
{
    __shared__ __align__(16) u16 Kbuf[2][64 * 64];   // 16 KB
    __shared__ __align__(16) u16 Vbuf[2][64 * 64];   // 16 KB
    // epilogue scratch lives in Kbuf[0] (per-wave 16x64 slice, post-barrier)

    const int tid  = threadIdx.x;
    const int lane = tid & 63;
    const int wave = tid >> 6;
    const int l15  = lane & 15;
    const int quad = lane >> 4;
    const int s7   = l15 & 7;
    const int bh = blockIdx.x, b = bh >> 4, h = bh & (H_ - 1);
    const int j  = blockIdx.y;                 // 0..15
    const int dg0 = j, dg1 = 31 - j;

    const u16* Qg = Qm + (size_t)b * S_ * D_ + h * HD_;
    const u16* Kg = Km + (size_t)b * S_ * D_ + h * HD_;
    const u16* Vg = Vtg + ((size_t)(b * H_ + h)) * HD_ * S_;

    bf16x8 qf0[2], qf1[2];
    {
        const u16* qp = Qg + (size_t)(dg0 * 64 + wave * 16 + l15) * D_ + quad * 8;
        qf0[0] = *(const bf16x8*)qp; qf0[1] = *(const bf16x8*)(qp + 32);
        qp = Qg + (size_t)(dg1 * 64 + wave * 16 + l15) * D_ + quad * 8;
        qf1[0] = *(const bf16x8*)qp; qf1[1] = *(const bf16x8*)(qp + 32);
    }

    f32x4 of0[4] = {}, of1[4] = {};
    float lacc0 = 0.f, lacc1 = 0.f;
    const int qloc = wave * 16 + l15;
    const int r8 = lane >> 3;
    const int csw = ((lane & 7) ^ r8) * 8;     // swizzled global chunk

    auto stage = [&](int t, int bsel) {
        u16* kb = Kbuf[bsel];
        u16* vb = Vbuf[bsel];
#pragma unroll
        for (int i = 0; i < 2; ++i) {
            const int row = wave * 16 + i * 8 + r8;
            gl_lds16(Kg + (size_t)(t * 64 + row) * D_ + csw,
                     kb + (wave * 16 + i * 8) * 64);
            gl_lds16(Vg + (size_t)row * S_ + t * 64 + csw,
                     vb + (wave * 16 + i * 8) * 64);
        }
    };

    auto pass = [&](const bf16x8 (&q)[2], f32x4 (&o)[4], float& la,
                    bool domask, const u16* kb, const u16* vb) {
        // S^T = K.Q^T (K frags read from LDS at point of use)
        f32x4 sf[4];
#pragma unroll
        for (int kt = 0; kt < 4; ++kt) {
            const u16* kp = kb + (kt * 16 + l15) * 64;
            bf16x8 k0 = *(const bf16x8*)(kp + ((quad    ) ^ s7) * 8);
            bf16x8 k1 = *(const bf16x8*)(kp + ((quad + 4) ^ s7) * 8);
            f32x4 a = {};
            a = __builtin_amdgcn_mfma_f32_16x16x32_bf16(k0, q[0], a, 0, 0, 0);
            a = __builtin_amdgcn_mfma_f32_16x16x32_bf16(k1, q[1], a, 0, 0, 0);
            sf[kt] = a;
        }
        // exp2 + pack P into w[kt][h] = keys kt*16+quad*4+{2h,2h+1}
        unsigned int w[4][2];
        float ls = 0.f;
        if (domask) {
#pragma unroll
            for (int kt = 0; kt < 4; ++kt)
#pragma unroll
                for (int hh = 0; hh < 2; ++hh) {
                    float v0 = sf[kt][2 * hh], v1 = sf[kt][2 * hh + 1];
                    if (kt * 16 + quad * 4 + 2 * hh     > qloc) v0 = -INFINITY;
                    if (kt * 16 + quad * 4 + 2 * hh + 1 > qloc) v1 = -INFINITY;
                    float p0 = __builtin_amdgcn_exp2f(v0);
                    float p1 = __builtin_amdgcn_exp2f(v1);
                    ls += p0 + p1;
                    w[kt][hh] = (__builtin_bit_cast(unsigned int, p0) >> 16) |
                                (__builtin_bit_cast(unsigned int, p1) & 0xFFFF0000u);
                }
        } else {
#pragma unroll
            for (int kt = 0; kt < 4; ++kt)
#pragma unroll
                for (int hh = 0; hh < 2; ++hh) {
                    float p0 = __builtin_amdgcn_exp2f(sf[kt][2 * hh]);
                    float p1 = __builtin_amdgcn_exp2f(sf[kt][2 * hh + 1]);
                    ls += p0 + p1;
                    w[kt][hh] = (__builtin_bit_cast(unsigned int, p0) >> 16) |
                                (__builtin_bit_cast(unsigned int, p1) & 0xFFFF0000u);
                }
        }
        la += ls;
        // C-layout -> B-layout on the VALU: per word-pair (g0,g1),
        // permlane32_swap gives a'=[g0_lo,g1_lo], b'=[g0_hi,g1_hi];
        // permlane16_swap(a',b') gives X=[g0@q0,g0@q2,g1@q0,g1@q2] and
        // Z=[g0@q1,g0@q3,g1@q1,g1@q3] = the B-fragment words directly.
        i32x4 f0, f1;
        {
            u32x2 t, r;
            t = __builtin_amdgcn_permlane32_swap(w[0][0], w[1][0], false, false);
            r = __builtin_amdgcn_permlane16_swap(t[0], t[1], false, false);
            f0.x = (int)r[0]; f0.z = (int)r[1];
            t = __builtin_amdgcn_permlane32_swap(w[0][1], w[1][1], false, false);
            r = __builtin_amdgcn_permlane16_swap(t[0], t[1], false, false);
            f0.y = (int)r[0]; f0.w = (int)r[1];
            t = __builtin_amdgcn_permlane32_swap(w[2][0], w[3][0], false, false);
            r = __builtin_amdgcn_permlane16_swap(t[0], t[1], false, false);
            f1.x = (int)r[0]; f1.z = (int)r[1];
            t = __builtin_amdgcn_permlane32_swap(w[2][1], w[3][1], false, false);
            r = __builtin_amdgcn_permlane16_swap(t[0], t[1], false, false);
            f1.y = (int)r[0]; f1.w = (int)r[1];
        }
        bf16x8 pf0 = __builtin_bit_cast(bf16x8, f0);
        bf16x8 pf1 = __builtin_bit_cast(bf16x8, f1);
        // ctx^T += Vt.P^T (V frags read from LDS at point of use)
#pragma unroll
        for (int dt = 0; dt < 4; ++dt) {
            const u16* vp = vb + (dt * 16 + l15) * 64;
            bf16x8 v0 = *(const bf16x8*)(vp + ((quad    ) ^ s7) * 8);
            bf16x8 v1 = *(const bf16x8*)(vp + ((quad + 4) ^ s7) * 8);
            o[dt] = __builtin_amdgcn_mfma_f32_16x16x32_bf16(v0, pf0, o[dt], 0, 0, 0);
            o[dt] = __builtin_amdgcn_mfma_f32_16x16x32_bf16(v1, pf1, o[dt], 0, 0, 0);
        }
    };

    const int T = 32 - j;
    stage(0, 0);
    for (int t = 0; t < T; ++t) {
        __syncthreads();                       // buf[t&1] ready (vmcnt drain)
        if (t + 1 < T) stage(t + 1, (t + 1) & 1);
        const u16* kb = Kbuf[t & 1];
        const u16* vb = Vbuf[t & 1];
        if (t <= dg0) pass(qf0, of0, lacc0, t == dg0, kb, vb);
        pass(qf1, of1, lacc1, t == dg1, kb, vb);   // runs every iteration
    }

    // all waves done reading K/V buffers -> reuse Kbuf[0] as epilogue scratch
    __syncthreads();
    u16* pw = &Kbuf[0][0] + wave * 16 * 64;
    auto epi = [&](const f32x4 (&o)[4], float la, int dgq) {
        float ls = la;
        ls += __shfl_xor(ls, 16);
        ls += __shfl_xor(ls, 32);
        const float inv = 1.f / ls;
#pragma unroll
        for (int dt = 0; dt < 4; ++dt) {
            const int g = dt * 16 + quad * 4;
            const int pos = ((g >> 3) ^ s7) * 8 + (g & 7);
            *(u16x4*)(pw + l15 * 64 + pos) =
                u16x4{f2b(o[dt][0] * inv), f2b(o[dt][1] * inv),
                      f2b(o[dt][2] * inv), f2b(o[dt][3] * inv)};
        }
        const int r  = lane >> 2;
        const int cp = lane & 3;
        u16x8 o0 = *(const u16x8*)(pw + r * 64 + ((2 * cp    ) ^ (r & 7)) * 8);
        u16x8 o1 = *(const u16x8*)(pw + r * 64 + ((2 * cp + 1) ^ (r & 7)) * 8);
        u16* op = Om + ((size_t)(b * S_ + dgq * 64 + wave * 16 + r)) * D_ + h * 64 + cp * 16;
        *(u16x8*)op = o0;
        *(u16x8*)(op + 8) = o1;
    };
    epi(of0, lacc0, dg0);
    epi(of1, lacc1, dg1);
}

// ---------------------------------------------------------------------------
extern "C" void kernel_launch(void* const* d_in, const int* in_sizes, int n_in,
                              void* d_out, int out_size, void* d_ws, size_t ws_size,
                              hipStream_t stream)
{
    (void)in_sizes; (void)n_in; (void)out_size; (void)ws_size;
    const float* x  = (const float*)d_in[0];
    const float* Wq = (const float*)d_in[1];
    const float* bq = (const float*)d_in[2];
    const float* Wk = (const float*)d_in[3];
    const float* bk = (const float*)d_in[4];
    const float* Wv = (const float*)d_in[5];
    const float* bv = (const float*)d_in[6];
    const float* Wo = (const float*)d_in[7];
    const float* bo = (const float*)d_in[8];

    const float cscale = 0.18033688011112042f;  // log2(e)/sqrt(64)

    u16* ws = (u16*)d_ws;
    const size_t MD = (size_t)M_ * D_;
    const size_t DD = (size_t)D_ * D_;
    u16* xb    = ws;            // bf16 [M, D]
    u16* Qb    = xb + MD;       // bf16 [B,S,H,HD], pre-scaled
    u16* Kb    = Qb + MD;       // bf16 [B,S,H,HD]
    u16* Vtb   = Kb + MD;       // bf16 [B,H,HD,S]
    u16* Cb    = Vtb + MD;      // ctx bf16 [M, D]
    u16* WqkvT = Cb + MD;       // bf16 [3072, 1024] (Q section pre-scaled)
    u16* WoT   = WqkvT + 3 * DD;

    cvt_k<<<M_ * D_ / 2048, 256, 0, stream>>>(x, xb);

    transpose4_k<<<dim3(D_ / 32, D_ / 32, 4), 256, 0, stream>>>(
        Wq, Wk, Wv, Wo, WqkvT, WoT, cscale);

    gemm_qkv256<<<dim3(M_ / QBM, N3_ / QBN), 512, 0, stream>>>(
        xb, WqkvT, bq, bk, bv, cscale, Qb, Kb, Vtb, M_, N3_, D_);

    attn_mfma_k<<<dim3(B_ * H_, 16), 256, 0, stream>>>(Qb, Kb, Vtb, Cb);

    gemm_core<1><<<dim3(M_ / BM, D_ / BN), 256, 0, stream>>>(
        Cb, WoT, bo, nullptr, nullptr, 1.0f, d_out, nullptr, nullptr, M_, D_, D_);
}